// Round 1
// baseline (1446.803 us; speedup 1.0000x reference)
//
#include <hip/hip_runtime.h>
#include <hip/hip_bf16.h>
#include <math.h>

// Problem constants
#define BB 8
#define SS 2048
#define TT (BB * SS)      // 16384 tokens
#define DM 256
#define DI 512
#define DSTATE 16
#define DCONV 4
#define NLAYERS 2
#define VOCAB 256
#define LOG_VOCAB 5.545177444479562f
#define RMS_EPS 1.1920929e-07f

// ---------------------------------------------------------------------------
// Generic fp32 tiled GEMM: C[M,N] = A[M,K] @ W[K,N]
// Block tile 64x64, 256 threads, 4x4 microtile, BK=16.
// M is always a multiple of 64 here; N,K guarded where needed (N=16 case).
// ---------------------------------------------------------------------------
#define BM 64
#define BN 64
#define BK 16

__global__ __launch_bounds__(256) void gemm_kernel(
    const float* __restrict__ A, const float* __restrict__ W,
    float* __restrict__ C, int M, int N, int K, int lda, int ldw, int ldc) {
  __shared__ float As[BK][BM + 1];
  __shared__ float Ws[BK][BN + 1];
  int tid = threadIdx.x;
  int tx = tid & 15;        // n direction
  int ty = tid >> 4;        // m direction
  int m0 = blockIdx.y * BM;
  int n0 = blockIdx.x * BN;
  float acc[4][4] = {};
  for (int k0 = 0; k0 < K; k0 += BK) {
    // A tile: 64 x 16
#pragma unroll
    for (int r = 0; r < 4; ++r) {
      int idx = tid + 256 * r;
      int m = idx >> 4;
      int k = idx & 15;
      As[k][m] = A[(size_t)(m0 + m) * lda + k0 + k];
    }
    // W tile: 16 x 64
#pragma unroll
    for (int r = 0; r < 4; ++r) {
      int idx = tid + 256 * r;
      int k = idx >> 6;
      int n = idx & 63;
      float v = 0.f;
      if (n0 + n < N) v = W[(size_t)(k0 + k) * ldw + n0 + n];
      Ws[k][n] = v;
    }
    __syncthreads();
#pragma unroll
    for (int kk = 0; kk < BK; ++kk) {
      float a[4], w[4];
#pragma unroll
      for (int i = 0; i < 4; ++i) a[i] = As[kk][ty * 4 + i];
#pragma unroll
      for (int j = 0; j < 4; ++j) w[j] = Ws[kk][tx * 4 + j];
#pragma unroll
      for (int i = 0; i < 4; ++i)
#pragma unroll
        for (int j = 0; j < 4; ++j) acc[i][j] += a[i] * w[j];
    }
    __syncthreads();
  }
#pragma unroll
  for (int i = 0; i < 4; ++i) {
    int m = m0 + ty * 4 + i;
#pragma unroll
    for (int j = 0; j < 4; ++j) {
      int n = n0 + tx * 4 + j;
      if (n < N) C[(size_t)m * ldc + n] = acc[i][j];
    }
  }
}

// ---------------------------------------------------------------------------
// Elementwise / small kernels
// ---------------------------------------------------------------------------
__global__ void aneg_kernel(const float* __restrict__ a_log, float* __restrict__ aneg, int n) {
  int i = blockIdx.x * blockDim.x + threadIdx.x;
  if (i < n) aneg[i] = -expf(a_log[i]);
}

__global__ void embed_kernel(const int* __restrict__ bytes, const float* __restrict__ ew,
                             float* __restrict__ x) {
  int t = blockIdx.x;
  int c = threadIdx.x;
  x[(size_t)t * DM + c] = ew[(size_t)bytes[t] * DM + c];
}

// causal depthwise conv (width 4, left pad 3) + bias + silu
__global__ void conv_silu_kernel(const float* __restrict__ xin, const float* __restrict__ cw,
                                 const float* __restrict__ cb, float* __restrict__ xc) {
  int t = blockIdx.x;
  int s = t & (SS - 1);
#pragma unroll
  for (int r = 0; r < 2; ++r) {
    int d = threadIdx.x + r * 256;
    float acc = cb[d];
#pragma unroll
    for (int k = 0; k < DCONV; ++k) {
      int sp = s - (DCONV - 1) + k;
      if (sp >= 0) acc += cw[d * DCONV + k] * xin[(size_t)(t - (DCONV - 1) + k) * DI + d];
    }
    xc[(size_t)t * DI + d] = acc / (1.f + expf(-acc));  // silu
  }
}

// SSM pointwise: reads dtlin in dtv, writes y*silu(z) back into dtv
__global__ void ssm_kernel(const float* __restrict__ xc, float* __restrict__ dtv,
                           const float* __restrict__ Bm, const float* __restrict__ Aneg,
                           const float* __restrict__ dtb, const float* __restrict__ Dp,
                           const float* __restrict__ z) {
  int t = blockIdx.x;
  __shared__ float Bs[DSTATE];
  if (threadIdx.x < DSTATE) Bs[threadIdx.x] = Bm[(size_t)t * DSTATE + threadIdx.x];
  __syncthreads();
#pragma unroll
  for (int r = 0; r < 2; ++r) {
    int d = threadIdx.x + r * 256;
    size_t idx = (size_t)t * DI + d;
    float dtl = dtv[idx] + dtb[d];
    // stable softplus: max(x,0) + log1p(exp(-|x|))
    float dt = fmaxf(dtl, 0.f) + log1pf(expf(-fabsf(dtl)));
    float sdot = 0.f;
#pragma unroll
    for (int n = 0; n < DSTATE; ++n) sdot += expf(Aneg[d * DSTATE + n] * dt) * Bs[n];
    float xcv = xc[idx];
    float y = dt * xcv * sdot + Dp[d] * xcv;
    float zv = z[idx];
    float sz = zv / (1.f + expf(-zv));
    dtv[idx] = y * sz;
  }
}

// x = rmsnorm(yout + x) * nw   (one 256-thread block per token)
__global__ void add_rmsnorm_kernel(const float* __restrict__ yout, float* __restrict__ x,
                                   const float* __restrict__ nw) {
  int t = blockIdx.x;
  int c = threadIdx.x;
  size_t idx = (size_t)t * DM + c;
  float v = yout[idx] + x[idx];
  float sq = v * v;
#pragma unroll
  for (int off = 32; off > 0; off >>= 1) sq += __shfl_down(sq, off);
  __shared__ float sm[4];
  int wave = c >> 6, lane = c & 63;
  if (lane == 0) sm[wave] = sq;
  __syncthreads();
  float ms = (sm[0] + sm[1] + sm[2] + sm[3]) * (1.f / DM);
  float r = rsqrtf(ms + RMS_EPS);
  x[idx] = v * r * nw[c];
}

// normalized entropy of softmax over 256 logits (one block per token)
__global__ void entropy_kernel(const float* __restrict__ logits, float* __restrict__ ent) {
  int t = blockIdx.x;
  int c = threadIdx.x;
  float l = logits[(size_t)t * VOCAB + c];
  int wave = c >> 6, lane = c & 63;
  __shared__ float sm[4];
  // max
  float m = l;
#pragma unroll
  for (int off = 32; off > 0; off >>= 1) m = fmaxf(m, __shfl_down(m, off));
  if (lane == 0) sm[wave] = m;
  __syncthreads();
  m = fmaxf(fmaxf(sm[0], sm[1]), fmaxf(sm[2], sm[3]));
  __syncthreads();
  // sum exp
  float e = expf(l - m);
  float s = e;
#pragma unroll
  for (int off = 32; off > 0; off >>= 1) s += __shfl_down(s, off);
  if (lane == 0) sm[wave] = s;
  __syncthreads();
  s = sm[0] + sm[1] + sm[2] + sm[3];
  float lse = logf(s);
  __syncthreads();
  // entropy
  float lp = l - m - lse;
  float h = expf(lp) * lp;
#pragma unroll
  for (int off = 32; off > 0; off >>= 1) h += __shfl_down(h, off);
  if (lane == 0) sm[wave] = h;
  __syncthreads();
  if (c == 0) ent[t] = -(sm[0] + sm[1] + sm[2] + sm[3]) / LOG_VOCAB;
}

// boundary scan + byte_to_patch + patch starts. 1 block, 8 waves (1 per batch).
__global__ void scan_kernel(const float* __restrict__ ent, float* __restrict__ btp_out,
                            int* __restrict__ btp_i, int* __restrict__ pstart,
                            int* __restrict__ npatch) {
  __shared__ unsigned long long masks[BB][32];
  __shared__ int wpre[BB][33];
  int tid = threadIdx.x;
  int w = tid >> 6, lane = tid & 63;
  int b = w;
  // phase A: compare bits wave-parallel, sequential size-scan on lane 0
  int size = 1;
  for (int w64 = 0; w64 < 32; ++w64) {
    int s = w64 * 64 + lane;
    float e = ent[b * SS + s];
    unsigned long long cb = __ballot(e > 0.5f);
    if (lane == 0) {
      unsigned long long bits;
      if (w64 == 0) {
        bits = 1ull;  // position 0 always boundary
        for (int j = 1; j < 64; ++j) {
          int c = (int)((cb >> j) & 1ull);
          int nb = c | (size >= 8);
          size = nb ? 1 : size + 1;
          bits |= ((unsigned long long)nb) << j;
        }
      } else if (cb == ~0ull) {
        bits = cb;  // all entropies above threshold: every position a boundary
        size = 1;
      } else {
        bits = 0ull;
        for (int j = 0; j < 64; ++j) {
          int c = (int)((cb >> j) & 1ull);
          int nb = c | (size >= 8);
          size = nb ? 1 : size + 1;
          bits |= ((unsigned long long)nb) << j;
        }
      }
      masks[w][w64] = bits;
    }
  }
  __syncthreads();
  // phase B: exclusive word prefix of boundary counts
  if (lane == 0) {
    int acc = 0;
    for (int i = 0; i < 32; ++i) {
      wpre[w][i] = acc;
      acc += __popcll(masks[w][i]);
    }
    wpre[w][32] = acc;
    npatch[b] = acc;
  }
  __syncthreads();
  // phase C: byte_to_patch = inclusive popcount prefix - 1; record patch starts
  for (int w64 = 0; w64 < 32; ++w64) {
    int s = w64 * 64 + lane;
    unsigned long long word = masks[w][w64];
    unsigned long long below =
        word & ((lane == 63) ? ~0ull : ((1ull << (lane + 1)) - 1ull));
    int btp = wpre[w][w64] + __popcll(below) - 1;
    btp_out[b * SS + s] = (float)btp;
    btp_i[b * SS + s] = btp;
    if ((word >> lane) & 1ull) pstart[b * SS + btp] = s;
  }
}

// per-patch mean pooling (contiguous ranges), zero-fill padding patches
__global__ void patch_kernel(const float* __restrict__ bemb, const int* __restrict__ pstart,
                             const int* __restrict__ npatch, float* __restrict__ pe_out,
                             float* __restrict__ plen_out) {
  int bp = blockIdx.x;
  int b = bp >> 11;        // / SS
  int p = bp & (SS - 1);   // % SS
  int c = threadIdx.x;
  int np = npatch[b];
  size_t outidx = (size_t)bp * DM + c;
  if (p >= np) {
    pe_out[outidx] = 0.f;
    if (c == 0) plen_out[bp] = 0.f;
    return;
  }
  int start = pstart[b * SS + p];
  int end = (p + 1 < np) ? pstart[b * SS + p + 1] : SS;
  float acc = 0.f;
  for (int t = start; t < end; ++t) acc += bemb[((size_t)b * SS + t) * DM + c];
  pe_out[outidx] = acc / (float)(end - start);
  if (c == 0) plen_out[bp] = (float)(end - start);
}

// ---------------------------------------------------------------------------
// Launcher
// ---------------------------------------------------------------------------
static inline void launch_gemm(const float* A, const float* W, float* C, int M, int N, int K,
                               int lda, int ldw, int ldc, hipStream_t stream) {
  dim3 grid((N + BN - 1) / BN, M / BM);
  gemm_kernel<<<grid, 256, 0, stream>>>(A, W, C, M, N, K, lda, ldw, ldc);
}

extern "C" void kernel_launch(void* const* d_in, const int* in_sizes, int n_in,
                              void* d_out, int out_size, void* d_ws, size_t ws_size,
                              hipStream_t stream) {
  const int* bytes = (const int*)d_in[0];
  const float* bemb = (const float*)d_in[1];
  const float* embed_w = (const float*)d_in[2];
  const float* in_proj_w = (const float*)d_in[3];
  const float* conv_w = (const float*)d_in[4];
  const float* conv_b = (const float*)d_in[5];
  const float* x_proj_w = (const float*)d_in[6];
  const float* dt_w = (const float*)d_in[7];
  const float* dt_b = (const float*)d_in[8];
  const float* A_log = (const float*)d_in[9];
  const float* D_param = (const float*)d_in[10];
  const float* out_w = (const float*)d_in[11];
  const float* norm_w = (const float*)d_in[12];
  const float* head_w = (const float*)d_in[13];

  float* out = (float*)d_out;
  float* pe_out = out;                              // (B,S,DM)
  float* plen_out = out + (size_t)TT * DM;          // (B,S)
  float* btp_out = plen_out + TT;                   // (B,S)

  // workspace layout (floats)
  float* wsf = (float*)d_ws;
  size_t off = 0;
  float* Aneg = wsf + off;  off += (size_t)NLAYERS * DI * DSTATE;       // 16384
  float* x    = wsf + off;  off += (size_t)TT * DM;                     // 4M
  float* bufA = wsf + off;  off += (size_t)TT * DI;                     // 8M (xin -> dtlin -> y)
  float* bufB = wsf + off;  off += (size_t)TT * DI;                     // 8M (z)
  float* bufC = wsf + off;  off += (size_t)TT * DI;                     // 8M (xc -> yout -> logits)
  float* Bm   = wsf + off;  off += (size_t)TT * DSTATE;                 // 256K
  float* ent  = wsf + off;  off += (size_t)TT;                          // 16K
  int* btp_i  = (int*)(wsf + off);  off += TT;
  int* pstart = (int*)(wsf + off);  off += TT;
  int* npatch = (int*)(wsf + off);  off += 64;

  // precompute A = -exp(A_log)
  aneg_kernel<<<(NLAYERS * DI * DSTATE + 255) / 256, 256, 0, stream>>>(
      A_log, Aneg, NLAYERS * DI * DSTATE);

  // embedding gather
  embed_kernel<<<TT, DM, 0, stream>>>(bytes, embed_w, x);

  for (int l = 0; l < NLAYERS; ++l) {
    const float* inW = in_proj_w + (size_t)l * DM * 2 * DI;
    const float* cw = conv_w + (size_t)l * DI * DCONV;
    const float* cb = conv_b + (size_t)l * DI;
    const float* xpW = x_proj_w + (size_t)l * DI * 2 * DSTATE;
    const float* dtW = dt_w + (size_t)l * DI * DI;
    const float* dtB = dt_b + (size_t)l * DI;
    const float* An = Aneg + (size_t)l * DI * DSTATE;
    const float* Dp = D_param + (size_t)l * DI;
    const float* oW = out_w + (size_t)l * DI * DM;
    const float* nW = norm_w + (size_t)l * DM;

    // x_in = x @ inW[:, :512]; z = x @ inW[:, 512:]
    launch_gemm(x, inW, bufA, TT, DI, DM, DM, 2 * DI, DI, stream);
    launch_gemm(x, inW + DI, bufB, TT, DI, DM, DM, 2 * DI, DI, stream);
    // xc = silu(conv(x_in) + cb)
    conv_silu_kernel<<<TT, 256, 0, stream>>>(bufA, cw, cb, bufC);
    // Bmat = xc @ xpW[:, :16]
    launch_gemm(bufC, xpW, Bm, TT, DSTATE, DI, DI, 2 * DSTATE, DSTATE, stream);
    // dtlin = xc @ dtW
    launch_gemm(bufC, dtW, bufA, TT, DI, DI, DI, DI, DI, stream);
    // y = (softplus(dtlin+dtb)*xc*sum_n exp(A*dt)*B + D*xc) * silu(z)  (in-place in bufA)
    ssm_kernel<<<TT, 256, 0, stream>>>(bufC, bufA, Bm, An, dtB, Dp, bufB);
    // yout = y @ oW
    launch_gemm(bufA, oW, bufC, TT, DM, DI, DI, DM, DM, stream);
    // x = rmsnorm(yout + x) * nW
    add_rmsnorm_kernel<<<TT, DM, 0, stream>>>(bufC, x, nW);
  }

  // logits = x @ head_w ; entropy
  launch_gemm(x, head_w, bufC, TT, VOCAB, DM, DM, VOCAB, VOCAB, stream);
  entropy_kernel<<<TT, VOCAB, 0, stream>>>(bufC, ent);

  // boundary scan -> byte_to_patch (+float copy straight to d_out)
  scan_kernel<<<1, 512, 0, stream>>>(ent, btp_out, btp_i, pstart, npatch);

  // patch mean pooling -> patch_embeddings, patch_lengths
  patch_kernel<<<TT, DM, 0, stream>>>(bemb, pstart, npatch, pe_out, plen_out);
}

// Round 2
// 611.530 us; speedup vs baseline: 2.3659x; 2.3659x over previous
//
#include <hip/hip_runtime.h>
#include <hip/hip_bf16.h>
#include <math.h>

// Problem constants
#define BB 8
#define SS 2048
#define TT (BB * SS)      // 16384 tokens
#define DM 256
#define DI 512
#define DSTATE 16
#define DCONV 4
#define NLAYERS 2
#define VOCAB 256
#define LOG_VOCAB 5.545177444479562f
#define RMS_EPS 1.1920929e-07f

typedef __attribute__((ext_vector_type(8))) __bf16 bf16x8;
typedef __attribute__((ext_vector_type(4))) float f32x4;

// ---------------------------------------------------------------------------
// bf16 MFMA GEMM (m97 structure): C[M,N] = A[M,K] @ Bt[N,K]^T
// 128x128 block tile, BK=32, 256 threads (4 waves, each 64x64),
// global_load_lds width-16 staging, 16x16x32 bf16 MFMA.
// M,N multiples of 128; K multiple of 32.
// ---------------------------------------------------------------------------
__device__ __forceinline__ void gl2lds16(const void* g, void* l) {
  __builtin_amdgcn_global_load_lds(
      (const __attribute__((address_space(1))) void*)g,
      (__attribute__((address_space(3))) void*)l, 16, 0, 0);
}

template <typename T> __device__ __forceinline__ T cvt_out(float v);
template <> __device__ __forceinline__ float cvt_out<float>(float v) { return v; }
template <> __device__ __forceinline__ __hip_bfloat16 cvt_out<__hip_bfloat16>(float v) {
  return __float2bfloat16(v);
}

template <typename OutT>
__global__ __launch_bounds__(256) void gemm_mfma(
    const __bf16* __restrict__ A,   // [M][K]
    const __bf16* __restrict__ Bt,  // [N][K]  (W^T)
    OutT* __restrict__ C,           // [M][N]
    int M, int N, int K) {
  __shared__ __align__(16) __bf16 As[128 * 32];
  __shared__ __align__(16) __bf16 Bs[128 * 32];
  int tid = threadIdx.x;
  int lane = tid & 63;
  int wave = tid >> 6;
  int wm = (wave & 1) * 64;
  int wn = (wave >> 1) * 64;
  int m0 = blockIdx.y * 128;
  int n0 = blockIdx.x * 128;

  // staging coords: thread covers 16B chunk (row r, k-chunk kc) and (row 64+r, kc)
  int r = tid >> 2;
  int kc = (tid & 3) * 8;

  // fragment coords
  int fr = lane & 15;
  int fk = (lane >> 4) * 8;

  f32x4 acc[4][4] = {};

  for (int k0 = 0; k0 < K; k0 += 32) {
    const __bf16* ga0 = A + (size_t)(m0 + r) * K + k0 + kc;
    const __bf16* ga1 = A + (size_t)(m0 + 64 + r) * K + k0 + kc;
    const __bf16* gb0 = Bt + (size_t)(n0 + r) * K + k0 + kc;
    const __bf16* gb1 = Bt + (size_t)(n0 + 64 + r) * K + k0 + kc;
    gl2lds16(ga0, As + r * 32 + kc);
    gl2lds16(ga1, As + (64 + r) * 32 + kc);
    gl2lds16(gb0, Bs + r * 32 + kc);
    gl2lds16(gb1, Bs + (64 + r) * 32 + kc);
    __syncthreads();  // compiler inserts vmcnt(0) drain before barrier

    bf16x8 af[4], bfr[4];
#pragma unroll
    for (int i = 0; i < 4; ++i) {
      af[i] = *(const bf16x8*)(As + (wm + i * 16 + fr) * 32 + fk);
      bfr[i] = *(const bf16x8*)(Bs + (wn + i * 16 + fr) * 32 + fk);
    }
#pragma unroll
    for (int i = 0; i < 4; ++i)
#pragma unroll
      for (int j = 0; j < 4; ++j)
        acc[i][j] = __builtin_amdgcn_mfma_f32_16x16x32_bf16(af[i], bfr[j], acc[i][j], 0, 0, 0);
    __syncthreads();  // protect LDS for next iteration's staging
  }

  // epilogue: C/D layout col=lane&15, row=(lane>>4)*4+reg  [m89-verified]
  int cr = (lane >> 4) * 4;
  int cc = lane & 15;
#pragma unroll
  for (int i = 0; i < 4; ++i) {
    int mrow = m0 + wm + i * 16 + cr;
#pragma unroll
    for (int j = 0; j < 4; ++j) {
      int ncol = n0 + wn + j * 16 + cc;
#pragma unroll
      for (int rg = 0; rg < 4; ++rg)
        C[(size_t)(mrow + rg) * N + ncol] = cvt_out<OutT>(acc[i][j][rg]);
    }
  }
}

// ---------------------------------------------------------------------------
// Weight prep: transpose + cast fp32 [K][N] -> bf16 [N][K]
// ---------------------------------------------------------------------------
__global__ void tcast_kernel(const float* __restrict__ src, __hip_bfloat16* __restrict__ dst,
                             int K, int N) {
  int i = blockIdx.x * 256 + threadIdx.x;
  if (i >= K * N) return;
  int n = i / K, k = i - n * K;
  dst[i] = __float2bfloat16(src[(size_t)k * N + n]);
}

__global__ void aneg_kernel(const float* __restrict__ a_log, float* __restrict__ aneg, int n) {
  int i = blockIdx.x * blockDim.x + threadIdx.x;
  if (i < n) aneg[i] = -expf(a_log[i]);
}

// embedding gather -> x fp32 + xb bf16
__global__ void embed_kernel(const int* __restrict__ bytes, const float* __restrict__ ew,
                             float* __restrict__ x, __hip_bfloat16* __restrict__ xb) {
  int t = blockIdx.x;
  int c = threadIdx.x;
  float v = ew[(size_t)bytes[t] * DM + c];
  x[(size_t)t * DM + c] = v;
  xb[(size_t)t * DM + c] = __float2bfloat16(v);
}

// causal depthwise conv (width 4, left pad 3) + bias + silu.
// xin = xz[:, 0:512] (row stride 1024, bf16). Writes xc bf16.
__global__ void conv_silu_kernel(const __hip_bfloat16* __restrict__ xz,
                                 const float* __restrict__ cw, const float* __restrict__ cb,
                                 __hip_bfloat16* __restrict__ xc) {
  int t = blockIdx.x;
  int s = t & (SS - 1);
#pragma unroll
  for (int rr = 0; rr < 2; ++rr) {
    int d = threadIdx.x + rr * 256;
    float acc = cb[d];
#pragma unroll
    for (int k = 0; k < DCONV; ++k) {
      int sp = s - (DCONV - 1) + k;
      if (sp >= 0)
        acc += cw[d * DCONV + k] *
               __bfloat162float(xz[(size_t)(t - (DCONV - 1) + k) * (2 * DI) + d]);
    }
    xc[(size_t)t * DI + d] = __float2bfloat16(acc / (1.f + expf(-acc)));  // silu
  }
}

// Bmat[t][n] = sum_k xc[t][k] * xpWt[n][k]   (n<16). 16 tokens per block.
__global__ void bmat_kernel(const __hip_bfloat16* __restrict__ xc,
                            const __hip_bfloat16* __restrict__ xpWt,
                            float* __restrict__ Bm) {
  int tid = threadIdx.x;
  int lane = tid & 63, wave = tid >> 6;
  int n = lane & 15, tsub = lane >> 4;
  int t = blockIdx.x * 16 + wave * 4 + tsub;
  const __hip_bfloat16* xr = xc + (size_t)t * DI;
  const __hip_bfloat16* wr = xpWt + (size_t)n * DI;
  float acc = 0.f;
#pragma unroll 8
  for (int k = 0; k < DI; ++k) acc += __bfloat162float(xr[k]) * __bfloat162float(wr[k]);
  Bm[(size_t)t * DSTATE + n] = acc;
}

// SSM pointwise: dty holds dtlin (bf16) in, y (bf16) out (in-place).
// z = xz[:, 512:1024].
__global__ void ssm_kernel(const __hip_bfloat16* __restrict__ xc,
                           __hip_bfloat16* __restrict__ dty,
                           const float* __restrict__ Bm, const float* __restrict__ Aneg,
                           const float* __restrict__ dtb, const float* __restrict__ Dp,
                           const __hip_bfloat16* __restrict__ xz) {
  int t = blockIdx.x;
  __shared__ float Bs[DSTATE];
  if (threadIdx.x < DSTATE) Bs[threadIdx.x] = Bm[(size_t)t * DSTATE + threadIdx.x];
  __syncthreads();
#pragma unroll
  for (int rr = 0; rr < 2; ++rr) {
    int d = threadIdx.x + rr * 256;
    size_t idx = (size_t)t * DI + d;
    float dtl = __bfloat162float(dty[idx]) + dtb[d];
    float dt = fmaxf(dtl, 0.f) + log1pf(expf(-fabsf(dtl)));  // stable softplus
    float sdot = 0.f;
#pragma unroll
    for (int n = 0; n < DSTATE; ++n) sdot += expf(Aneg[d * DSTATE + n] * dt) * Bs[n];
    float xcv = __bfloat162float(xc[idx]);
    float y = dt * xcv * sdot + Dp[d] * xcv;
    float zv = __bfloat162float(xz[(size_t)t * (2 * DI) + DI + d]);
    float sz = zv / (1.f + expf(-zv));
    dty[idx] = __float2bfloat16(y * sz);
  }
}

// x = rmsnorm(yout + x) * nw ; also refresh xb (bf16 copy)
__global__ void add_rmsnorm_kernel(const float* __restrict__ yout, float* __restrict__ x,
                                   const float* __restrict__ nw,
                                   __hip_bfloat16* __restrict__ xb) {
  int t = blockIdx.x;
  int c = threadIdx.x;
  size_t idx = (size_t)t * DM + c;
  float v = yout[idx] + x[idx];
  float sq = v * v;
#pragma unroll
  for (int off = 32; off > 0; off >>= 1) sq += __shfl_down(sq, off);
  __shared__ float sm[4];
  int wave = c >> 6, lane = c & 63;
  if (lane == 0) sm[wave] = sq;
  __syncthreads();
  float ms = (sm[0] + sm[1] + sm[2] + sm[3]) * (1.f / DM);
  float rr = rsqrtf(ms + RMS_EPS);
  float o = v * rr * nw[c];
  x[idx] = o;
  xb[idx] = __float2bfloat16(o);
}

// normalized entropy of softmax over 256 logits (one block per token)
__global__ void entropy_kernel(const float* __restrict__ logits, float* __restrict__ ent) {
  int t = blockIdx.x;
  int c = threadIdx.x;
  float l = logits[(size_t)t * VOCAB + c];
  int wave = c >> 6, lane = c & 63;
  __shared__ float sm[4];
  float m = l;
#pragma unroll
  for (int off = 32; off > 0; off >>= 1) m = fmaxf(m, __shfl_down(m, off));
  if (lane == 0) sm[wave] = m;
  __syncthreads();
  m = fmaxf(fmaxf(sm[0], sm[1]), fmaxf(sm[2], sm[3]));
  __syncthreads();
  float e = expf(l - m);
  float s = e;
#pragma unroll
  for (int off = 32; off > 0; off >>= 1) s += __shfl_down(s, off);
  if (lane == 0) sm[wave] = s;
  __syncthreads();
  s = sm[0] + sm[1] + sm[2] + sm[3];
  float lse = logf(s);
  __syncthreads();
  float lp = l - m - lse;
  float h = expf(lp) * lp;
#pragma unroll
  for (int off = 32; off > 0; off >>= 1) h += __shfl_down(h, off);
  if (lane == 0) sm[wave] = h;
  __syncthreads();
  if (c == 0) ent[t] = -(sm[0] + sm[1] + sm[2] + sm[3]) / LOG_VOCAB;
}

// boundary scan + byte_to_patch + patch starts. 1 block, 8 waves (1 per batch).
__global__ void scan_kernel(const float* __restrict__ ent, float* __restrict__ btp_out,
                            int* __restrict__ btp_i, int* __restrict__ pstart,
                            int* __restrict__ npatch) {
  __shared__ unsigned long long masks[BB][32];
  __shared__ int wpre[BB][33];
  int tid = threadIdx.x;
  int w = tid >> 6, lane = tid & 63;
  int b = w;
  int size = 1;
  for (int w64 = 0; w64 < 32; ++w64) {
    int s = w64 * 64 + lane;
    float e = ent[b * SS + s];
    unsigned long long cb = __ballot(e > 0.5f);
    if (lane == 0) {
      unsigned long long bits;
      if (w64 == 0) {
        bits = 1ull;
        for (int j = 1; j < 64; ++j) {
          int c = (int)((cb >> j) & 1ull);
          int nb = c | (size >= 8);
          size = nb ? 1 : size + 1;
          bits |= ((unsigned long long)nb) << j;
        }
      } else if (cb == ~0ull) {
        bits = cb;
        size = 1;
      } else {
        bits = 0ull;
        for (int j = 0; j < 64; ++j) {
          int c = (int)((cb >> j) & 1ull);
          int nb = c | (size >= 8);
          size = nb ? 1 : size + 1;
          bits |= ((unsigned long long)nb) << j;
        }
      }
      masks[w][w64] = bits;
    }
  }
  __syncthreads();
  if (lane == 0) {
    int acc = 0;
    for (int i = 0; i < 32; ++i) {
      wpre[w][i] = acc;
      acc += __popcll(masks[w][i]);
    }
    wpre[w][32] = acc;
    npatch[b] = acc;
  }
  __syncthreads();
  for (int w64 = 0; w64 < 32; ++w64) {
    int s = w64 * 64 + lane;
    unsigned long long word = masks[w][w64];
    unsigned long long below =
        word & ((lane == 63) ? ~0ull : ((1ull << (lane + 1)) - 1ull));
    int btp = wpre[w][w64] + __popcll(below) - 1;
    btp_out[b * SS + s] = (float)btp;
    btp_i[b * SS + s] = btp;
    if ((word >> lane) & 1ull) pstart[b * SS + btp] = s;
  }
}

// per-patch mean pooling (contiguous ranges), zero-fill padding patches
__global__ void patch_kernel(const float* __restrict__ bemb, const int* __restrict__ pstart,
                             const int* __restrict__ npatch, float* __restrict__ pe_out,
                             float* __restrict__ plen_out) {
  int bp = blockIdx.x;
  int b = bp >> 11;
  int p = bp & (SS - 1);
  int c = threadIdx.x;
  int np = npatch[b];
  size_t outidx = (size_t)bp * DM + c;
  if (p >= np) {
    pe_out[outidx] = 0.f;
    if (c == 0) plen_out[bp] = 0.f;
    return;
  }
  int start = pstart[b * SS + p];
  int end = (p + 1 < np) ? pstart[b * SS + p + 1] : SS;
  float acc = 0.f;
  for (int t = start; t < end; ++t) acc += bemb[((size_t)b * SS + t) * DM + c];
  pe_out[outidx] = acc / (float)(end - start);
  if (c == 0) plen_out[bp] = (float)(end - start);
}

// ---------------------------------------------------------------------------
// Launcher
// ---------------------------------------------------------------------------
template <typename OutT>
static inline void launch_gemm(const __hip_bfloat16* A, const __hip_bfloat16* Bt, OutT* C,
                               int M, int N, int K, hipStream_t stream) {
  dim3 grid(N / 128, M / 128);
  gemm_mfma<OutT><<<grid, 256, 0, stream>>>((const __bf16*)A, (const __bf16*)Bt, C, M, N, K);
}

extern "C" void kernel_launch(void* const* d_in, const int* in_sizes, int n_in,
                              void* d_out, int out_size, void* d_ws, size_t ws_size,
                              hipStream_t stream) {
  const int* bytes = (const int*)d_in[0];
  const float* bemb = (const float*)d_in[1];
  const float* embed_w = (const float*)d_in[2];
  const float* in_proj_w = (const float*)d_in[3];
  const float* conv_w = (const float*)d_in[4];
  const float* conv_b = (const float*)d_in[5];
  const float* x_proj_w = (const float*)d_in[6];
  const float* dt_w = (const float*)d_in[7];
  const float* dt_b = (const float*)d_in[8];
  const float* A_log = (const float*)d_in[9];
  const float* D_param = (const float*)d_in[10];
  const float* out_w = (const float*)d_in[11];
  const float* norm_w = (const float*)d_in[12];
  const float* head_w = (const float*)d_in[13];

  float* out = (float*)d_out;
  float* pe_out = out;                      // (B,S,DM)
  float* plen_out = out + (size_t)TT * DM;  // (B,S)
  float* btp_out = plen_out + TT;           // (B,S)

  // workspace (byte allocator, 256B aligned)
  char* wsb = (char*)d_ws;
  size_t off = 0;
  auto alloc = [&](size_t bytes) -> void* {
    void* p = wsb + off;
    off += (bytes + 255) & ~(size_t)255;
    return p;
  };
  float* Aneg = (float*)alloc((size_t)NLAYERS * DI * DSTATE * 4);
  float* x = (float*)alloc((size_t)TT * DM * 4);
  __hip_bfloat16* xb = (__hip_bfloat16*)alloc((size_t)TT * DM * 2);
  __hip_bfloat16* xz = (__hip_bfloat16*)alloc((size_t)TT * 2 * DI * 2);
  __hip_bfloat16* xc = (__hip_bfloat16*)alloc((size_t)TT * DI * 2);
  __hip_bfloat16* dty = (__hip_bfloat16*)alloc((size_t)TT * DI * 2);
  float* yl = (float*)alloc((size_t)TT * DM * 4);  // yout / logits
  float* Bm = (float*)alloc((size_t)TT * DSTATE * 4);
  float* ent = (float*)alloc((size_t)TT * 4);
  int* btp_i = (int*)alloc((size_t)TT * 4);
  int* pstart = (int*)alloc((size_t)TT * 4);
  int* npatch = (int*)alloc(256);
  __hip_bfloat16* inWt = (__hip_bfloat16*)alloc((size_t)NLAYERS * 2 * DI * DM * 2);   // [1024][256]
  __hip_bfloat16* dtWt = (__hip_bfloat16*)alloc((size_t)NLAYERS * DI * DI * 2);       // [512][512]
  __hip_bfloat16* oWt = (__hip_bfloat16*)alloc((size_t)NLAYERS * DM * DI * 2);        // [256][512]
  __hip_bfloat16* xpWt = (__hip_bfloat16*)alloc((size_t)NLAYERS * 32 * DI * 2);       // [32][512]
  __hip_bfloat16* headWt = (__hip_bfloat16*)alloc((size_t)VOCAB * DM * 2);            // [256][256]

  // ---- weight prep ----
  aneg_kernel<<<(NLAYERS * DI * DSTATE + 255) / 256, 256, 0, stream>>>(
      A_log, Aneg, NLAYERS * DI * DSTATE);
  for (int l = 0; l < NLAYERS; ++l) {
    tcast_kernel<<<(DM * 2 * DI + 255) / 256, 256, 0, stream>>>(
        in_proj_w + (size_t)l * DM * 2 * DI, inWt + (size_t)l * 2 * DI * DM, DM, 2 * DI);
    tcast_kernel<<<(DI * DI + 255) / 256, 256, 0, stream>>>(
        dt_w + (size_t)l * DI * DI, dtWt + (size_t)l * DI * DI, DI, DI);
    tcast_kernel<<<(DI * DM + 255) / 256, 256, 0, stream>>>(
        out_w + (size_t)l * DI * DM, oWt + (size_t)l * DM * DI, DI, DM);
    tcast_kernel<<<(DI * 32 + 255) / 256, 256, 0, stream>>>(
        x_proj_w + (size_t)l * DI * 32, xpWt + (size_t)l * 32 * DI, DI, 32);
  }
  tcast_kernel<<<(DM * VOCAB + 255) / 256, 256, 0, stream>>>(head_w, headWt, DM, VOCAB);

  // ---- entropy model ----
  embed_kernel<<<TT, DM, 0, stream>>>(bytes, embed_w, x, xb);

  for (int l = 0; l < NLAYERS; ++l) {
    const float* cw = conv_w + (size_t)l * DI * DCONV;
    const float* cb = conv_b + (size_t)l * DI;
    const float* dtB = dt_b + (size_t)l * DI;
    const float* An = Aneg + (size_t)l * DI * DSTATE;
    const float* Dp = D_param + (size_t)l * DI;
    const float* nW = norm_w + (size_t)l * DM;

    // xz = xb @ inW  (both halves at once: N=1024)
    launch_gemm(xb, inWt + (size_t)l * 2 * DI * DM, (__hip_bfloat16*)xz, TT, 2 * DI, DM, stream);
    // xc = silu(conv(xz[:, :512]) + cb)
    conv_silu_kernel<<<TT, 256, 0, stream>>>(xz, cw, cb, xc);
    // Bmat = xc @ xpW[:, :16]
    bmat_kernel<<<TT / 16, 256, 0, stream>>>(xc, xpWt + (size_t)l * 32 * DI, Bm);
    // dtlin = xc @ dtW
    launch_gemm(xc, dtWt + (size_t)l * DI * DI, dty, TT, DI, DI, stream);
    // y = (softplus(dtlin+dtb)*xc*sum_n exp(A*dt)*B + D*xc) * silu(z)
    ssm_kernel<<<TT, 256, 0, stream>>>(xc, dty, Bm, An, dtB, Dp, xz);
    // yout = y @ oW (fp32 out for residual+rmsnorm)
    launch_gemm(dty, oWt + (size_t)l * DM * DI, yl, TT, DM, DI, stream);
    // x = rmsnorm(yout + x) * nW ; refresh xb
    add_rmsnorm_kernel<<<TT, DM, 0, stream>>>(yl, x, nW, xb);
  }

  // logits = xb @ head_w ; entropy
  launch_gemm(xb, headWt, yl, TT, VOCAB, DM, stream);
  entropy_kernel<<<TT, VOCAB, 0, stream>>>(yl, ent);

  // boundary scan -> byte_to_patch
  scan_kernel<<<1, 512, 0, stream>>>(ent, btp_out, btp_i, pstart, npatch);

  // patch mean pooling -> patch_embeddings, patch_lengths
  patch_kernel<<<TT, DM, 0, stream>>>(bemb, pstart, npatch, pe_out, plen_out);
}